// Round 10
// baseline (338.209 us; speedup 1.0000x reference)
//
#include <hip/hip_runtime.h>

#define BATCH   262144
#define IN_DIM  28
#define HID     128
#define LAT     64
#define NCODES  512
#define NBLK    512             // 512 rows per block (16 waves x 32 rows)
#define WVS     16
#define NWAVE   (NBLK * WVS)    // 8192

#define BLOB_SHORTS 20480       // bf16 LDS tables: lw1+lw2+ld1
#define BLOB_F32    864         // e2 + biases
#define BLOB_BYTES  (BLOB_SHORTS * 2 + BLOB_F32 * 4)   // 44416
#define ACT_BASE    (BLOB_BYTES / 2)                    // short offset 22208
#define LDS_BYTES   (BLOB_BYTES + WVS * 1024 * 2)       // 77184 -> 2 blocks/CU

typedef short v8s __attribute__((ext_vector_type(8)));
typedef float v4f __attribute__((ext_vector_type(4)));

union v8u { v8s s; uint4 u; };

__device__ __forceinline__ unsigned short f2bf(float f) {   // RNE (prep only)
  unsigned u = __float_as_uint(f);
  u += 0x7fffu + ((u >> 16) & 1u);
  return (unsigned short)(u >> 16);
}
// truncating f32->bf16 (validated r7-r9: absmax 0.0015 < thr 0.020)
__device__ __forceinline__ unsigned short hi16(float f) {
  return (unsigned short)(__float_as_uint(f) >> 16);
}
// pack two truncated bf16 (lo, hi) in ONE v_perm_b32
__device__ __forceinline__ unsigned pk(float hi, float lo) {
  return __builtin_amdgcn_perm(__float_as_uint(hi), __float_as_uint(lo), 0x07060302u);
}

// Bank-swizzled LDS table offset (shorts): 16B col-blocks XOR-permuted by row.
__device__ __forceinline__ int toff(int base, int row, int col, int SB) {
  return base + row * (SB * 8) + ((((col >> 3) ^ row) & (SB - 1)) << 3) + (col & 7);
}
// XOR-swizzled 16x64 half-tile (per-wave 2 KB act buffer), offsets in shorts.
__device__ __forceinline__ int hswz(int row, int col) {   // row 0..15, col 0..63
  int g = col >> 3;
  return (g * 16 + ((row ^ g) & 15)) * 8 + (col & 7);
}

// LDS blob (short offsets):
//   lw1 @0      [128 n][32 k]  SB=4   enc_w1^T (k>=28 zero)
//   lw2 @4096   [64 n][128 k]  SB=16  enc_w2^T
//   ld1 @12288  [128 n][64 k]  SB=8   bf16(-0.5*dec_w1^T)  (cancels -2q)
// fp32 @ byte 40960: e2[512], b1[128], b2[64], db1[128], db2[32 pad0]
// GLOBAL tables (L2-resident, read on the VMEM pipe — r10 change):
//   cbg  [512 c][64 d] bf16(-2*codebook), row-major
//   ld2g [32 n][128 k] bf16(dec_w2^T), row-major (n>=28 zero)
__global__ __launch_bounds__(256) void vq_prep(
    const float* __restrict__ ew1, const float* __restrict__ eb1,
    const float* __restrict__ ew2, const float* __restrict__ eb2,
    const float* __restrict__ cb,  const float* __restrict__ dw1,
    const float* __restrict__ db1, const float* __restrict__ dw2,
    const float* __restrict__ db2,
    unsigned short* __restrict__ blob,
    unsigned short* __restrict__ cbg,
    unsigned short* __restrict__ ld2g) {
  int i = blockIdx.x * 256 + threadIdx.x;
  float* fb = (float*)(blob + BLOB_SHORTS);
  if (i < 4096) {                       // lw1
    int row = i >> 5, col = i & 31;
    float v = (col < IN_DIM) ? ew1[col * HID + row] : 0.f;
    blob[toff(0, row, col, 4)] = f2bf(v);
  } else if (i < 12288) {               // lw2
    int j = i - 4096; int row = j >> 7, col = j & 127;
    blob[toff(4096, row, col, 16)] = f2bf(ew2[col * LAT + row]);
  } else if (i < 20480) {               // ld1 = -0.5*dec_w1^T
    int j = i - 12288; int row = j >> 6, col = j & 63;
    blob[toff(12288, row, col, 8)] = f2bf(-0.5f * dw1[col * HID + row]);
  } else if (i < 21344) {               // f32 region
    int k = i - 20480;
    if (k < 512) {
      float s = 0.f;
      for (int d = 0; d < LAT; ++d) { float v = cb[k * LAT + d]; s += v * v; }
      fb[k] = s;
    } else if (k < 640) fb[k] = eb1[k - 512];
    else if (k < 704)   fb[k] = eb2[k - 640];
    else if (k < 832)   fb[k] = db1[k - 704];
    else                fb[k] = (k - 832 < IN_DIM) ? db2[k - 832] : 0.f;
  } else if (i < 54112) {               // cbg = -2*cb, row-major
    int j = i - 21344;
    cbg[j] = f2bf(-2.0f * cb[j]);
  } else if (i < 58208) {               // ld2g = dec_w2^T, row-major
    int j = i - 54112; int n = j >> 7, k = j & 127;
    ld2g[j] = (n < IN_DIM) ? f2bf(dw2[k * IN_DIM + n]) : (unsigned short)0;
  }
}

// ---------------- fused main kernel ----------------
// r9 was DS-pipe-bound (~82% busy by audit). r10: codebook + dec_w2 moved to
// GLOBAL (VMEM pipe, L2-resident) — argmin's 64 b128/tile leave the DS pipe;
// blob shrinks 118->44 KB so LDS/block = 77184 B -> 2 blocks/CU -> 8
// waves/SIMD (was 4). Grid 512 x 16 waves x 2 tiles. launch_bounds(1024,8)
// pins VGPR<=64 to keep 32 waves/CU resident.
__global__ __launch_bounds__(1024, 8) void vq_main(
    const float* __restrict__ x,
    const unsigned short* __restrict__ blob,
    const unsigned short* __restrict__ cbg,
    const unsigned short* __restrict__ ld2g,
    float* __restrict__ out, float* __restrict__ partials) {

  extern __shared__ __align__(16) char smem[];
  unsigned short* L  = (unsigned short*)smem;
  float*          LF = (float*)(smem + BLOB_SHORTS * 2);

  const int tid  = threadIdx.x;
  const int wave = tid >> 6;
  const int lane = tid & 63;
  const int quad = lane >> 4;
  const int lm   = lane & 15;

  // ---- stage LDS tables (one-time) ----
  {
    const float4* src = (const float4*)blob;
    float4* dst = (float4*)smem;
#pragma unroll
    for (int it = 0; it < 3; ++it) {
      int idx = it * 1024 + tid;
      if (idx < BLOB_BYTES / 16) dst[idx] = src[idx];
    }
  }
  __syncthreads();

  unsigned short* A = L + ACT_BASE + wave * 1024;   // 16x64 half-tile buffer
  const int rbase = blockIdx.x * 512 + wave * 32;
  float racc = 0.f, vqacc = 0.f;

#pragma unroll 1
  for (int t = 0; t < 2; ++t) {
    const int r0 = rbase + t * 16;

    // ---- x load & bf16 pack ----
    v8u a1;
    {
      const float* xp = x + (size_t)(r0 + lm) * IN_DIM + quad * 8;
      float4 v0 = *(const float4*)xp;
      float4 v1 = {0.f, 0.f, 0.f, 0.f};
      if (quad != 3) v1 = *(const float4*)(xp + 4);
      a1.u.x = pk(v0.y, v0.x); a1.u.y = pk(v0.w, v0.z);
      a1.u.z = pk(v1.y, v1.x); a1.u.w = pk(v1.w, v1.z);
    }

    // ---- stages 1+2, two 64-col halves through the 2 KB buffer ----
    v4f accz[4];
#pragma unroll
    for (int nt2 = 0; nt2 < 4; ++nt2) {
      float bv = LF[640 + nt2 * 16 + lm];
      accz[nt2] = (v4f){bv, bv, bv, bv};
    }
#pragma unroll
    for (int h = 0; h < 2; ++h) {
#pragma unroll
      for (int j = 0; j < 4; ++j) {
        int nt = 4 * h + j;
        int row = nt * 16 + lm;
        v8s frag = *(const v8s*)&L[toff(0, row, quad * 8, 4)];
        float bv = LF[512 + row];
        v4f seed = {bv, bv, bv, bv};
        v4f acc = __builtin_amdgcn_mfma_f32_16x16x32_bf16(a1.s, frag, seed, 0, 0, 0);
#pragma unroll
        for (int r = 0; r < 4; ++r)
          A[hswz(quad * 4 + r, j * 16 + lm)] = hi16(fmaxf(acc[r], 0.f));
      }
      v8s ha0 = *(const v8s*)&A[hswz(lm, quad * 8)];
      v8s ha1 = *(const v8s*)&A[hswz(lm, 32 + quad * 8)];
#pragma unroll
      for (int nt2 = 0; nt2 < 4; ++nt2) {
        int row = nt2 * 16 + lm;
        v8s f0 = *(const v8s*)&L[toff(4096, row, (2 * h) * 32 + quad * 8, 16)];
        accz[nt2] = __builtin_amdgcn_mfma_f32_16x16x32_bf16(ha0, f0, accz[nt2], 0, 0, 0);
        v8s f1 = *(const v8s*)&L[toff(4096, row, (2 * h + 1) * 32 + quad * 8, 16)];
        accz[nt2] = __builtin_amdgcn_mfma_f32_16x16x32_bf16(ha1, f1, accz[nt2], 0, 0, 0);
      }
    }

    // ---- z (16x64) -> buffer; z2 partial; A-frags ----
    float z2p[4];
#pragma unroll
    for (int nt2 = 0; nt2 < 4; ++nt2)
#pragma unroll
      for (int r = 0; r < 4; ++r)
        A[hswz(quad * 4 + r, nt2 * 16 + lm)] = hi16(accz[nt2][r]);
#pragma unroll
    for (int r = 0; r < 4; ++r)
      z2p[r] = accz[0][r] * accz[0][r] + accz[1][r] * accz[1][r]
             + accz[2][r] * accz[2][r] + accz[3][r] * accz[3][r];
    v8s za0 = *(const v8s*)&A[hswz(lm, quad * 8)];
    v8s za1 = *(const v8s*)&A[hswz(lm, 32 + quad * 8)];

    // ---- argmin: dist = e2 + z.(-2e); codebook from GLOBAL (L2/VMEM pipe) ----
    float bd[4]; int bc[4];
#pragma unroll
    for (int r = 0; r < 4; ++r) { bd[r] = 3.4e38f; bc[r] = 0x7fffffff; }
#pragma unroll 2
    for (int ct = 0; ct < 32; ++ct) {
      int row = ct * 16 + lm;
      v8s cb0 = *(const v8s*)(cbg + row * 64 + quad * 8);
      v8s cb1 = *(const v8s*)(cbg + row * 64 + 32 + quad * 8);
      float ev = LF[row];
      v4f seed = {ev, ev, ev, ev};
      v4f acc = __builtin_amdgcn_mfma_f32_16x16x32_bf16(za0, cb0, seed, 0, 0, 0);
      acc = __builtin_amdgcn_mfma_f32_16x16x32_bf16(za1, cb1, acc, 0, 0, 0);
#pragma unroll
      for (int r = 0; r < 4; ++r)
        if (acc[r] < bd[r]) { bd[r] = acc[r]; bc[r] = row; }   // ascending -> lowest idx on tie
    }

    // ---- 16-lane reduce (argmin + z2), vq partial, idx broadcast ----
#pragma unroll
    for (int off = 1; off < 16; off <<= 1) {
#pragma unroll
      for (int r = 0; r < 4; ++r) {
        float od = __shfl_xor(bd[r], off, 64);
        int   oc = __shfl_xor(bc[r], off, 64);
        if (od < bd[r] || (od == bd[r] && oc < bc[r])) { bd[r] = od; bc[r] = oc; }
        z2p[r] += __shfl_xor(z2p[r], off, 64);
      }
    }
    if (lm == 0) {
#pragma unroll
      for (int r = 0; r < 4; ++r) vqacc += z2p[r] + bd[r];   // ||z-q||^2
    }
    int i0 = __shfl(bc[0], (lm >> 2) << 4, 64);
    int i1 = __shfl(bc[1], (lm >> 2) << 4, 64);
    int i2 = __shfl(bc[2], (lm >> 2) << 4, 64);
    int i3 = __shfl(bc[3], (lm >> 2) << 4, 64);
    int sel = lm & 3;
    int idxv = sel == 0 ? i0 : sel == 1 ? i1 : sel == 2 ? i2 : i3;

    // ---- stages 5+6, two halves; qa gathered from GLOBAL cbg (-2q), ld1 -0.5 ----
    v8s qa0 = *(const v8s*)(cbg + idxv * 64 + quad * 8);
    v8s qa1 = *(const v8s*)(cbg + idxv * 64 + 32 + quad * 8);
    v4f a6[2];
#pragma unroll
    for (int nt6 = 0; nt6 < 2; ++nt6) {
      float bv = LF[832 + nt6 * 16 + lm];
      a6[nt6] = (v4f){bv, bv, bv, bv};
    }
#pragma unroll
    for (int h = 0; h < 2; ++h) {
#pragma unroll
      for (int j = 0; j < 4; ++j) {
        int nt = 4 * h + j;
        int row = nt * 16 + lm;
        v8s b0 = *(const v8s*)&L[toff(12288, row, quad * 8, 8)];
        v8s b1 = *(const v8s*)&L[toff(12288, row, 32 + quad * 8, 8)];
        float bv = LF[704 + row];
        v4f seed = {bv, bv, bv, bv};
        v4f acc = __builtin_amdgcn_mfma_f32_16x16x32_bf16(qa0, b0, seed, 0, 0, 0);
        acc = __builtin_amdgcn_mfma_f32_16x16x32_bf16(qa1, b1, acc, 0, 0, 0);
#pragma unroll
        for (int r = 0; r < 4; ++r)
          A[hswz(quad * 4 + r, j * 16 + lm)] = hi16(fmaxf(acc[r], 0.f));
      }
      v8s hd0 = *(const v8s*)&A[hswz(lm, quad * 8)];
      v8s hd1 = *(const v8s*)&A[hswz(lm, 32 + quad * 8)];
      // stage-6 partial accumulation from GLOBAL ld2g: ks = 2h, 2h+1
#pragma unroll
      for (int nt6 = 0; nt6 < 2; ++nt6) {
        int row = nt6 * 16 + lm;
        v8s f0 = *(const v8s*)(ld2g + row * 128 + (2 * h) * 32 + quad * 8);
        a6[nt6] = __builtin_amdgcn_mfma_f32_16x16x32_bf16(hd0, f0, a6[nt6], 0, 0, 0);
        v8s f1 = *(const v8s*)(ld2g + row * 128 + (2 * h + 1) * 32 + quad * 8);
        a6[nt6] = __builtin_amdgcn_mfma_f32_16x16x32_bf16(hd1, f1, a6[nt6], 0, 0, 0);
      }
    }

    // ---- store recon + loss partial ----
#pragma unroll
    for (int nt6 = 0; nt6 < 2; ++nt6) {
      int n = nt6 * 16 + lm;
      bool valid = (n < IN_DIM);
#pragma unroll
      for (int r = 0; r < 4; ++r) {
        float rec = a6[nt6][r];
        if (valid) {
          size_t o = (size_t)(r0 + quad * 4 + r) * IN_DIM + n;
          out[o] = rec;
          float dv = rec - x[o];
          racc += dv * dv;
        }
      }
    }
  }

  // ---- per-wave butterfly, per-wave partial store (no atomics) ----
#pragma unroll
  for (int off = 1; off < 64; off <<= 1) {
    racc  += __shfl_xor(racc, off, 64);
    vqacc += __shfl_xor(vqacc, off, 64);
  }
  if (lane == 0) {
    size_t w = (size_t)blockIdx.x * WVS + wave;
    partials[w * 2]     = racc;
    partials[w * 2 + 1] = vqacc;
  }
}

// ---------------- finalize: reduce per-wave partials, write scalars ----------------
__global__ __launch_bounds__(256) void vq_fin(const float* __restrict__ partials,
                                              float* __restrict__ out) {
  float r = 0.f, v = 0.f;
  for (int i = threadIdx.x; i < NWAVE; i += 256) {
    r += partials[2 * i];
    v += partials[2 * i + 1];
  }
#pragma unroll
  for (int off = 1; off < 64; off <<= 1) {
    r += __shfl_xor(r, off, 64);
    v += __shfl_xor(v, off, 64);
  }
  __shared__ float s[4][2];
  int w = threadIdx.x >> 6;
  if ((threadIdx.x & 63) == 0) { s[w][0] = r; s[w][1] = v; }
  __syncthreads();
  if (threadIdx.x == 0) {
    float R = s[0][0] + s[1][0] + s[2][0] + s[3][0];
    float V = s[0][1] + s[1][1] + s[2][1] + s[3][1];
    out[7340032] = R * (1.0f / 7340032.0f);          // recon_loss = S / (B*28)
    out[7340033] = V * (1.25f / 16777216.0f);        // vq_loss = 1.25 * S / (B*64)
  }
}

extern "C" void kernel_launch(void* const* d_in, const int* in_sizes, int n_in,
                              void* d_out, int out_size, void* d_ws, size_t ws_size,
                              hipStream_t stream) {
  const float* x   = (const float*)d_in[0];
  const float* ew1 = (const float*)d_in[1];
  const float* eb1 = (const float*)d_in[2];
  const float* ew2 = (const float*)d_in[3];
  const float* eb2 = (const float*)d_in[4];
  const float* cb  = (const float*)d_in[5];
  const float* dw1 = (const float*)d_in[6];
  const float* db1 = (const float*)d_in[7];
  const float* dw2 = (const float*)d_in[8];
  const float* db2 = (const float*)d_in[9];

  char* ws = (char*)d_ws;
  unsigned short* blob = (unsigned short*)(ws + 0);        //  44416 B
  unsigned short* cbg  = (unsigned short*)(ws + 44416);    //  65536 B
  unsigned short* ld2g = (unsigned short*)(ws + 109952);   //   8192 B
  float* partials      = (float*)(ws + 118144);            //  65536 B

  float* out = (float*)d_out;

  // allow >64 KB dynamic LDS
  (void)hipFuncSetAttribute((const void*)vq_main,
                            hipFuncAttributeMaxDynamicSharedMemorySize, LDS_BYTES);

  vq_prep<<<228, 256, 0, stream>>>(ew1, eb1, ew2, eb2, cb, dw1, db1, dw2, db2,
                                   blob, cbg, ld2g);
  vq_main<<<NBLK, 1024, LDS_BYTES, stream>>>(x, blob, cbg, ld2g, out, partials);
  vq_fin<<<1, 256, 0, stream>>>(partials, out);
}

// Round 11
// 279.620 us; speedup vs baseline: 1.2095x; 1.2095x over previous
//
#include <hip/hip_runtime.h>

#define BATCH   262144
#define IN_DIM  28
#define HID     128
#define LAT     64
#define NCODES  512
#define NBLK    512             // 512 rows per block (16 waves x 32 rows)
#define WVS     16
#define NWAVE   (NBLK * WVS)    // 8192

#define BLOB_SHORTS 20480       // bf16 LDS tables: lw1+lw2+ld1
#define BLOB_F32    864         // e2 + biases
#define BLOB_BYTES  (BLOB_SHORTS * 2 + BLOB_F32 * 4)   // 44416
#define ACT_BASE    (BLOB_BYTES / 2)                    // short offset 22208
#define LDS_BYTES   (BLOB_BYTES + WVS * 1024 * 2)       // 77184

typedef short v8s __attribute__((ext_vector_type(8)));
typedef float v4f __attribute__((ext_vector_type(4)));

union v8u { v8s s; uint4 u; };

__device__ __forceinline__ unsigned short f2bf(float f) {   // RNE (prep only)
  unsigned u = __float_as_uint(f);
  u += 0x7fffu + ((u >> 16) & 1u);
  return (unsigned short)(u >> 16);
}
// truncating f32->bf16 (validated r7-r10: absmax 0.0015 < thr 0.020)
__device__ __forceinline__ unsigned short hi16(float f) {
  return (unsigned short)(__float_as_uint(f) >> 16);
}
// pack two truncated bf16 (lo, hi) in ONE v_perm_b32
__device__ __forceinline__ unsigned pk(float hi, float lo) {
  return __builtin_amdgcn_perm(__float_as_uint(hi), __float_as_uint(lo), 0x07060302u);
}

// Bank-swizzled LDS table offset (shorts): 16B col-blocks XOR-permuted by row.
__device__ __forceinline__ int toff(int base, int row, int col, int SB) {
  return base + row * (SB * 8) + ((((col >> 3) ^ row) & (SB - 1)) << 3) + (col & 7);
}
// XOR-swizzled 16x64 half-tile (per-wave 2 KB act buffer), offsets in shorts.
__device__ __forceinline__ int hswz(int row, int col) {   // row 0..15, col 0..63
  int g = col >> 3;
  return (g * 16 + ((row ^ g) & 15)) * 8 + (col & 7);
}

// LDS blob (short offsets):
//   lw1 @0      [128 n][32 k]  SB=4   enc_w1^T (k>=28 zero)
//   lw2 @4096   [64 n][128 k]  SB=16  enc_w2^T
//   ld1 @12288  [128 n][64 k]  SB=8   bf16(-0.5*dec_w1^T)  (cancels -2q)
// fp32 @ byte 40960: e2[512], b1[128], b2[64], db1[128], db2[32 pad0]
// GLOBAL tables (L2-resident, VMEM pipe): cbg = -2*cb [512][64]; ld2g [32][128]
__global__ __launch_bounds__(256) void vq_prep(
    const float* __restrict__ ew1, const float* __restrict__ eb1,
    const float* __restrict__ ew2, const float* __restrict__ eb2,
    const float* __restrict__ cb,  const float* __restrict__ dw1,
    const float* __restrict__ db1, const float* __restrict__ dw2,
    const float* __restrict__ db2,
    unsigned short* __restrict__ blob,
    unsigned short* __restrict__ cbg,
    unsigned short* __restrict__ ld2g) {
  int i = blockIdx.x * 256 + threadIdx.x;
  float* fb = (float*)(blob + BLOB_SHORTS);
  if (i < 4096) {                       // lw1
    int row = i >> 5, col = i & 31;
    float v = (col < IN_DIM) ? ew1[col * HID + row] : 0.f;
    blob[toff(0, row, col, 4)] = f2bf(v);
  } else if (i < 12288) {               // lw2
    int j = i - 4096; int row = j >> 7, col = j & 127;
    blob[toff(4096, row, col, 16)] = f2bf(ew2[col * LAT + row]);
  } else if (i < 20480) {               // ld1 = -0.5*dec_w1^T
    int j = i - 12288; int row = j >> 6, col = j & 63;
    blob[toff(12288, row, col, 8)] = f2bf(-0.5f * dw1[col * HID + row]);
  } else if (i < 21344) {               // f32 region
    int k = i - 20480;
    if (k < 512) {
      float s = 0.f;
      for (int d = 0; d < LAT; ++d) { float v = cb[k * LAT + d]; s += v * v; }
      fb[k] = s;
    } else if (k < 640) fb[k] = eb1[k - 512];
    else if (k < 704)   fb[k] = eb2[k - 640];
    else if (k < 832)   fb[k] = db1[k - 704];
    else                fb[k] = (k - 832 < IN_DIM) ? db2[k - 832] : 0.f;
  } else if (i < 54112) {               // cbg = -2*cb, row-major
    int j = i - 21344;
    cbg[j] = f2bf(-2.0f * cb[j]);
  } else if (i < 58208) {               // ld2g = dec_w2^T, row-major
    int j = i - 54112; int n = j >> 7, k = j & 127;
    ld2g[j] = (n < IN_DIM) ? f2bf(dw2[k * IN_DIM + n]) : (unsigned short)0;
  }
}

// ---------------- fused main kernel ----------------
// r9 was DS-pipe-bound (~82% busy). r10 moved codebook+dec_w2 to GLOBAL
// (VMEM/L2 pipe) but the (1024,8) launch-bounds hint crushed the allocator
// to 32 arch VGPRs -> 550 MB scratch spill. r11: SAME kernel, hint removed
// (r9 compiled this body shape at VGPR=64, no spill). 1 block/CU guaranteed
// (4 waves/SIMD); 2 blocks if allocator lands <=64 unified.
__global__ __launch_bounds__(1024) void vq_main(
    const float* __restrict__ x,
    const unsigned short* __restrict__ blob,
    const unsigned short* __restrict__ cbg,
    const unsigned short* __restrict__ ld2g,
    float* __restrict__ out, float* __restrict__ partials) {

  extern __shared__ __align__(16) char smem[];
  unsigned short* L  = (unsigned short*)smem;
  float*          LF = (float*)(smem + BLOB_SHORTS * 2);

  const int tid  = threadIdx.x;
  const int wave = tid >> 6;
  const int lane = tid & 63;
  const int quad = lane >> 4;
  const int lm   = lane & 15;

  // ---- stage LDS tables (one-time) ----
  {
    const float4* src = (const float4*)blob;
    float4* dst = (float4*)smem;
#pragma unroll
    for (int it = 0; it < 3; ++it) {
      int idx = it * 1024 + tid;
      if (idx < BLOB_BYTES / 16) dst[idx] = src[idx];
    }
  }
  __syncthreads();

  unsigned short* A = L + ACT_BASE + wave * 1024;   // 16x64 half-tile buffer
  const int rbase = blockIdx.x * 512 + wave * 32;
  float racc = 0.f, vqacc = 0.f;

#pragma unroll 1
  for (int t = 0; t < 2; ++t) {
    const int r0 = rbase + t * 16;

    // ---- x load & bf16 pack ----
    v8u a1;
    {
      const float* xp = x + (size_t)(r0 + lm) * IN_DIM + quad * 8;
      float4 v0 = *(const float4*)xp;
      float4 v1 = {0.f, 0.f, 0.f, 0.f};
      if (quad != 3) v1 = *(const float4*)(xp + 4);
      a1.u.x = pk(v0.y, v0.x); a1.u.y = pk(v0.w, v0.z);
      a1.u.z = pk(v1.y, v1.x); a1.u.w = pk(v1.w, v1.z);
    }

    // ---- stages 1+2, two 64-col halves through the 2 KB buffer ----
    v4f accz[4];
#pragma unroll
    for (int nt2 = 0; nt2 < 4; ++nt2) {
      float bv = LF[640 + nt2 * 16 + lm];
      accz[nt2] = (v4f){bv, bv, bv, bv};
    }
#pragma unroll
    for (int h = 0; h < 2; ++h) {
#pragma unroll
      for (int j = 0; j < 4; ++j) {
        int nt = 4 * h + j;
        int row = nt * 16 + lm;
        v8s frag = *(const v8s*)&L[toff(0, row, quad * 8, 4)];
        float bv = LF[512 + row];
        v4f seed = {bv, bv, bv, bv};
        v4f acc = __builtin_amdgcn_mfma_f32_16x16x32_bf16(a1.s, frag, seed, 0, 0, 0);
#pragma unroll
        for (int r = 0; r < 4; ++r)
          A[hswz(quad * 4 + r, j * 16 + lm)] = hi16(fmaxf(acc[r], 0.f));
      }
      v8s ha0 = *(const v8s*)&A[hswz(lm, quad * 8)];
      v8s ha1 = *(const v8s*)&A[hswz(lm, 32 + quad * 8)];
#pragma unroll
      for (int nt2 = 0; nt2 < 4; ++nt2) {
        int row = nt2 * 16 + lm;
        v8s f0 = *(const v8s*)&L[toff(4096, row, (2 * h) * 32 + quad * 8, 16)];
        accz[nt2] = __builtin_amdgcn_mfma_f32_16x16x32_bf16(ha0, f0, accz[nt2], 0, 0, 0);
        v8s f1 = *(const v8s*)&L[toff(4096, row, (2 * h + 1) * 32 + quad * 8, 16)];
        accz[nt2] = __builtin_amdgcn_mfma_f32_16x16x32_bf16(ha1, f1, accz[nt2], 0, 0, 0);
      }
    }

    // ---- z (16x64) -> buffer; z2 partial; A-frags ----
    float z2p[4];
#pragma unroll
    for (int nt2 = 0; nt2 < 4; ++nt2)
#pragma unroll
      for (int r = 0; r < 4; ++r)
        A[hswz(quad * 4 + r, nt2 * 16 + lm)] = hi16(accz[nt2][r]);
#pragma unroll
    for (int r = 0; r < 4; ++r)
      z2p[r] = accz[0][r] * accz[0][r] + accz[1][r] * accz[1][r]
             + accz[2][r] * accz[2][r] + accz[3][r] * accz[3][r];
    v8s za0 = *(const v8s*)&A[hswz(lm, quad * 8)];
    v8s za1 = *(const v8s*)&A[hswz(lm, 32 + quad * 8)];

    // ---- argmin: dist = e2 + z.(-2e); codebook from GLOBAL (L2/VMEM pipe) ----
    float bd[4]; int bc[4];
#pragma unroll
    for (int r = 0; r < 4; ++r) { bd[r] = 3.4e38f; bc[r] = 0x7fffffff; }
#pragma unroll 2
    for (int ct = 0; ct < 32; ++ct) {
      int row = ct * 16 + lm;
      v8s cb0 = *(const v8s*)(cbg + row * 64 + quad * 8);
      v8s cb1 = *(const v8s*)(cbg + row * 64 + 32 + quad * 8);
      float ev = LF[row];
      v4f seed = {ev, ev, ev, ev};
      v4f acc = __builtin_amdgcn_mfma_f32_16x16x32_bf16(za0, cb0, seed, 0, 0, 0);
      acc = __builtin_amdgcn_mfma_f32_16x16x32_bf16(za1, cb1, acc, 0, 0, 0);
#pragma unroll
      for (int r = 0; r < 4; ++r)
        if (acc[r] < bd[r]) { bd[r] = acc[r]; bc[r] = row; }   // ascending -> lowest idx on tie
    }

    // ---- 16-lane reduce (argmin + z2), vq partial, idx broadcast ----
#pragma unroll
    for (int off = 1; off < 16; off <<= 1) {
#pragma unroll
      for (int r = 0; r < 4; ++r) {
        float od = __shfl_xor(bd[r], off, 64);
        int   oc = __shfl_xor(bc[r], off, 64);
        if (od < bd[r] || (od == bd[r] && oc < bc[r])) { bd[r] = od; bc[r] = oc; }
        z2p[r] += __shfl_xor(z2p[r], off, 64);
      }
    }
    if (lm == 0) {
#pragma unroll
      for (int r = 0; r < 4; ++r) vqacc += z2p[r] + bd[r];   // ||z-q||^2
    }
    int i0 = __shfl(bc[0], (lm >> 2) << 4, 64);
    int i1 = __shfl(bc[1], (lm >> 2) << 4, 64);
    int i2 = __shfl(bc[2], (lm >> 2) << 4, 64);
    int i3 = __shfl(bc[3], (lm >> 2) << 4, 64);
    int sel = lm & 3;
    int idxv = sel == 0 ? i0 : sel == 1 ? i1 : sel == 2 ? i2 : i3;

    // ---- stages 5+6, two halves; qa from GLOBAL cbg (-2q), ld1 -0.5 ----
    v8s qa0 = *(const v8s*)(cbg + idxv * 64 + quad * 8);
    v8s qa1 = *(const v8s*)(cbg + idxv * 64 + 32 + quad * 8);
    v4f a6[2];
#pragma unroll
    for (int nt6 = 0; nt6 < 2; ++nt6) {
      float bv = LF[832 + nt6 * 16 + lm];
      a6[nt6] = (v4f){bv, bv, bv, bv};
    }
#pragma unroll
    for (int h = 0; h < 2; ++h) {
#pragma unroll
      for (int j = 0; j < 4; ++j) {
        int nt = 4 * h + j;
        int row = nt * 16 + lm;
        v8s b0 = *(const v8s*)&L[toff(12288, row, quad * 8, 8)];
        v8s b1 = *(const v8s*)&L[toff(12288, row, 32 + quad * 8, 8)];
        float bv = LF[704 + row];
        v4f seed = {bv, bv, bv, bv};
        v4f acc = __builtin_amdgcn_mfma_f32_16x16x32_bf16(qa0, b0, seed, 0, 0, 0);
        acc = __builtin_amdgcn_mfma_f32_16x16x32_bf16(qa1, b1, acc, 0, 0, 0);
#pragma unroll
        for (int r = 0; r < 4; ++r)
          A[hswz(quad * 4 + r, j * 16 + lm)] = hi16(fmaxf(acc[r], 0.f));
      }
      v8s hd0 = *(const v8s*)&A[hswz(lm, quad * 8)];
      v8s hd1 = *(const v8s*)&A[hswz(lm, 32 + quad * 8)];
      // stage-6 partial accumulation from GLOBAL ld2g: ks = 2h, 2h+1
#pragma unroll
      for (int nt6 = 0; nt6 < 2; ++nt6) {
        int row = nt6 * 16 + lm;
        v8s f0 = *(const v8s*)(ld2g + row * 128 + (2 * h) * 32 + quad * 8);
        a6[nt6] = __builtin_amdgcn_mfma_f32_16x16x32_bf16(hd0, f0, a6[nt6], 0, 0, 0);
        v8s f1 = *(const v8s*)(ld2g + row * 128 + (2 * h + 1) * 32 + quad * 8);
        a6[nt6] = __builtin_amdgcn_mfma_f32_16x16x32_bf16(hd1, f1, a6[nt6], 0, 0, 0);
      }
    }

    // ---- store recon + loss partial ----
#pragma unroll
    for (int nt6 = 0; nt6 < 2; ++nt6) {
      int n = nt6 * 16 + lm;
      bool valid = (n < IN_DIM);
#pragma unroll
      for (int r = 0; r < 4; ++r) {
        float rec = a6[nt6][r];
        if (valid) {
          size_t o = (size_t)(r0 + quad * 4 + r) * IN_DIM + n;
          out[o] = rec;
          float dv = rec - x[o];
          racc += dv * dv;
        }
      }
    }
  }

  // ---- per-wave butterfly, per-wave partial store (no atomics) ----
#pragma unroll
  for (int off = 1; off < 64; off <<= 1) {
    racc  += __shfl_xor(racc, off, 64);
    vqacc += __shfl_xor(vqacc, off, 64);
  }
  if (lane == 0) {
    size_t w = (size_t)blockIdx.x * WVS + wave;
    partials[w * 2]     = racc;
    partials[w * 2 + 1] = vqacc;
  }
}

// ---------------- finalize: reduce per-wave partials, write scalars ----------------
__global__ __launch_bounds__(256) void vq_fin(const float* __restrict__ partials,
                                              float* __restrict__ out) {
  float r = 0.f, v = 0.f;
  for (int i = threadIdx.x; i < NWAVE; i += 256) {
    r += partials[2 * i];
    v += partials[2 * i + 1];
  }
#pragma unroll
  for (int off = 1; off < 64; off <<= 1) {
    r += __shfl_xor(r, off, 64);
    v += __shfl_xor(v, off, 64);
  }
  __shared__ float s[4][2];
  int w = threadIdx.x >> 6;
  if ((threadIdx.x & 63) == 0) { s[w][0] = r; s[w][1] = v; }
  __syncthreads();
  if (threadIdx.x == 0) {
    float R = s[0][0] + s[1][0] + s[2][0] + s[3][0];
    float V = s[0][1] + s[1][1] + s[2][1] + s[3][1];
    out[7340032] = R * (1.0f / 7340032.0f);          // recon_loss = S / (B*28)
    out[7340033] = V * (1.25f / 16777216.0f);        // vq_loss = 1.25 * S / (B*64)
  }
}

extern "C" void kernel_launch(void* const* d_in, const int* in_sizes, int n_in,
                              void* d_out, int out_size, void* d_ws, size_t ws_size,
                              hipStream_t stream) {
  const float* x   = (const float*)d_in[0];
  const float* ew1 = (const float*)d_in[1];
  const float* eb1 = (const float*)d_in[2];
  const float* ew2 = (const float*)d_in[3];
  const float* eb2 = (const float*)d_in[4];
  const float* cb  = (const float*)d_in[5];
  const float* dw1 = (const float*)d_in[6];
  const float* db1 = (const float*)d_in[7];
  const float* dw2 = (const float*)d_in[8];
  const float* db2 = (const float*)d_in[9];

  char* ws = (char*)d_ws;
  unsigned short* blob = (unsigned short*)(ws + 0);        //  44416 B
  unsigned short* cbg  = (unsigned short*)(ws + 44416);    //  65536 B
  unsigned short* ld2g = (unsigned short*)(ws + 109952);   //   8192 B
  float* partials      = (float*)(ws + 118144);            //  65536 B

  float* out = (float*)d_out;

  // allow >64 KB dynamic LDS
  (void)hipFuncSetAttribute((const void*)vq_main,
                            hipFuncAttributeMaxDynamicSharedMemorySize, LDS_BYTES);

  vq_prep<<<228, 256, 0, stream>>>(ew1, eb1, ew2, eb2, cb, dw1, db1, dw2, db2,
                                   blob, cbg, ld2g);
  vq_main<<<NBLK, 1024, LDS_BYTES, stream>>>(x, blob, cbg, ld2g, out, partials);
  vq_fin<<<1, 256, 0, stream>>>(partials, out);
}